// Round 1
// baseline (202.282 us; speedup 1.0000x reference)
//
#include <hip/hip_runtime.h>
#include <hip/hip_bf16.h>

// Problem constants
#define HH 256
#define WW 256
#define BB 4
#define CC 3
#define HW 65536          // H*W
#define NM 24             // 2*B*C masks (0..11 lab, 12..23 pred)
#define BIGF 1e9f
#define LIMITF 331776.0f  // 576*576
#define EPSF 1e-5f

// ---------------------------------------------------------------------------
// Pass 1: row-wise squared distance to nearest zero (exact match to
// min_k f[i,k]+(j-k)^2 with f in {0, 1e9}: result is nearest-zero-dist^2,
// or exactly 1e9 if the row has no zeros).
// grid: 24*256 blocks (mask, row), 256 threads (col).
// ---------------------------------------------------------------------------
__global__ __launch_bounds__(256) void k_rowpass(const float* __restrict__ pred,
                                                 const int* __restrict__ lab,
                                                 float* __restrict__ dbuf) {
    int blk = blockIdx.x;
    int i = blk & 255;        // row
    int m = blk >> 8;         // mask 0..23
    int j = threadIdx.x;      // col
    int bc = (m < 12) ? m : (m - 12);
    int b = bc / 3, c = bc % 3;

    int maskbit;
    if (m < 12) {
        maskbit = (lab[(b << 16) + (i << 8) + j] == c);
    } else {
        const float* pb = pred + (((size_t)(b * 3)) << 16) + (i << 8) + j;
        float p0 = pb[0];
        float p1 = pb[(size_t)1 << 16];
        float p2 = pb[(size_t)2 << 16];
        int am = 0; float v = p0;
        if (p1 > v) { am = 1; v = p1; }
        if (p2 > v) { am = 2; }
        maskbit = (am == c);
    }

    __shared__ unsigned long long zmask[4];
    unsigned long long zb = __ballot(maskbit == 0);   // zero-pixel bitmap, 64 lanes
    if ((threadIdx.x & 63) == 0) zmask[threadIdx.x >> 6] = zb;
    __syncthreads();

    int bestd = 512;  // sentinel > any possible distance (<=255)
    #pragma unroll
    for (int w2 = 0; w2 < 4; ++w2) {
        unsigned long long zm = zmask[w2];
        int base = w2 << 6;
        int rel = j - base;
        unsigned long long mle;   // bits at positions <= rel
        if (rel >= 63)      mle = ~0ULL;
        else if (rel < 0)   mle = 0ULL;
        else                mle = (2ULL << rel) - 1ULL;
        unsigned long long zl = zm & mle;
        if (zl) {
            int p = base + 63 - __clzll(zl);
            int d = j - p;
            if (d < bestd) bestd = d;
        }
        unsigned long long zr = zm & ~mle;
        if (zr) {
            int p = base + __ffsll((unsigned long long)zr) - 1;
            int d = p - j;
            if (d < bestd) bestd = d;
        }
    }
    float d1;
    if (bestd >= 512) d1 = BIGF;
    else { float fd = (float)bestd; d1 = fd * fd; }
    dbuf[(((size_t)m) << 16) + (i << 8) + j] = d1;
}

// ---------------------------------------------------------------------------
// Pass 2: column-wise min-plus with parabola: d[i,j] = min_k d1[k,j]+(i-k)^2.
// One block owns 16 columns of one mask; 256x16 tile in LDS; each thread
// produces 16 outputs (same column, rows ibase+16r) so the k-loop amortizes
// one LDS broadcast read over 16 fma+fmin updates. In-place write (tile is
// fully loaded before the barrier; blocks own disjoint columns).
// Also reduces the per-mask max of d (for normalization) via atomicMax.
// grid: 24*16 blocks, 256 threads.
// ---------------------------------------------------------------------------
__global__ __launch_bounds__(256) void k_colpass(float* __restrict__ dbuf,
                                                 float* __restrict__ mask_max) {
    int blk = blockIdx.x;
    int m = blk >> 4;
    int j0 = (blk & 15) << 4;
    __shared__ float tile[256 * 16];   // [row][jj], 16 KB
    float* base = dbuf + (((size_t)m) << 16);

    #pragma unroll
    for (int it = 0; it < 16; ++it) {
        int idx = (it << 8) + threadIdx.x;
        int row = idx >> 4, jj = idx & 15;
        tile[idx] = base[(row << 8) + j0 + jj];
    }
    __syncthreads();

    int jj = threadIdx.x & 15;
    int ibase = threadIdx.x >> 4;   // 0..15
    float dmin[16];
    #pragma unroll
    for (int r = 0; r < 16; ++r) dmin[r] = 3e38f;

    for (int k = 0; k < 256; ++k) {
        float fk = tile[(k << 4) + jj];      // broadcast within 4-lane groups
        float d0 = (float)(ibase - k);
        #pragma unroll
        for (int r = 0; r < 16; ++r) {
            float dk = d0 + (float)(r << 4);
            dmin[r] = fminf(dmin[r], fmaf(dk, dk, fk));
        }
    }

    float lmax = 0.0f;
    #pragma unroll
    for (int r = 0; r < 16; ++r) {
        int i = ibase + (r << 4);
        base[(i << 8) + j0 + jj] = dmin[r];
        lmax = fmaxf(lmax, dmin[r]);
    }

    // block max -> per-mask atomicMax (values >= 0: int ordering == float)
    #pragma unroll
    for (int off = 32; off; off >>= 1)
        lmax = fmaxf(lmax, __shfl_down(lmax, off, 64));
    __shared__ float wmax[4];
    if ((threadIdx.x & 63) == 0) wmax[threadIdx.x >> 6] = lmax;
    __syncthreads();
    if (threadIdx.x == 0) {
        float mx = fmaxf(fmaxf(wmax[0], wmax[1]), fmaxf(wmax[2], wmax[3]));
        atomicMax((int*)&mask_max[m], __float_as_int(mx));
    }
}

// ---------------------------------------------------------------------------
// Per-pixel cosine sim + per-batch reduction.
// sim = (sp*sl + [argmax==lab]) / (sqrt(sp^2+1)*sqrt(sl^2+1)), where
// sp/sl = sum_c sqrt(d)/(min(sqrt(dmax),LIMIT)+eps).
// grid: 1024 blocks x 256 (each block entirely inside one batch).
// ---------------------------------------------------------------------------
__global__ __launch_bounds__(256) void k_final(const float* __restrict__ pred,
                                               const int* __restrict__ lab,
                                               const float* __restrict__ dbuf,
                                               const float* __restrict__ mask_max,
                                               float* __restrict__ batch_sum,
                                               int* __restrict__ batch_fg) {
    int p = blockIdx.x * 256 + threadIdx.x;   // [0, B*HW)
    int b = p >> 16;
    int pix = p & 65535;

    int lv = lab[p];
    const float* pb = pred + (((size_t)(b * 3)) << 16) + pix;
    float p0 = pb[0];
    float p1 = pb[(size_t)1 << 16];
    float p2 = pb[(size_t)2 << 16];
    int am = 0; float v = p0;
    if (p1 > v) { am = 1; v = p1; }
    if (p2 > v) { am = 2; }

    float slab = 0.0f, spred = 0.0f;
    #pragma unroll
    for (int c = 0; c < 3; ++c) {
        int ml = b * 3 + c;
        float dl = dbuf[(((size_t)ml) << 16) + pix];
        float mlmax = fminf(sqrtf(mask_max[ml]), LIMITF);
        slab += sqrtf(dl) / (mlmax + EPSF);
        float dp = dbuf[(((size_t)(ml + 12)) << 16) + pix];
        float mpmax = fminf(sqrtf(mask_max[ml + 12]), LIMITF);
        spred += sqrtf(dp) / (mpmax + EPSF);
    }

    float dot = spred * slab + ((am == lv) ? 1.0f : 0.0f);
    float na = sqrtf(spred * spred + 1.0f);
    float nb = sqrtf(slab * slab + 1.0f);
    float sim = dot / (fmaxf(na, 1e-8f) * fmaxf(nb, 1e-8f));

    unsigned long long fg = __ballot(lv > 0);

    #pragma unroll
    for (int off = 32; off; off >>= 1)
        sim += __shfl_down(sim, off, 64);
    __shared__ float wsum[4];
    if ((threadIdx.x & 63) == 0) wsum[threadIdx.x >> 6] = sim;
    __syncthreads();
    if (threadIdx.x == 0)
        atomicAdd(&batch_sum[b], wsum[0] + wsum[1] + wsum[2] + wsum[3]);
    if ((threadIdx.x & 63) == 0 && fg)
        atomicOr(&batch_fg[b], 1);
}

// ---------------------------------------------------------------------------
// loss = sum_b has_fg ? (1 - mean sim) : 0, / B; nan_to_num.
// ---------------------------------------------------------------------------
__global__ void k_finalize(const float* __restrict__ batch_sum,
                           const int* __restrict__ batch_fg,
                           float* __restrict__ out) {
    if (threadIdx.x == 0 && blockIdx.x == 0) {
        float loss = 0.0f;
        for (int b = 0; b < BB; ++b) {
            float lb = 1.0f - batch_sum[b] * (1.0f / (float)HW);
            if (batch_fg[b]) loss += lb;
        }
        loss *= (1.0f / (float)BB);
        if (isnan(loss)) loss = 0.0f;
        else if (isinf(loss)) loss = (loss > 0.0f) ? 1.0f : 0.0f;
        out[0] = loss;
    }
}

extern "C" void kernel_launch(void* const* d_in, const int* in_sizes, int n_in,
                              void* d_out, int out_size, void* d_ws, size_t ws_size,
                              hipStream_t stream) {
    const float* pred = (const float*)d_in[0];   // [4,3,256,256] f32
    const int*   lab  = (const int*)d_in[1];     // [4,256,256] i32

    char* wsb = (char*)d_ws;
    float* dbuf      = (float*)wsb;                               // 24*65536 f32 = 6 MB
    size_t stats_off = (size_t)NM * HW * sizeof(float);
    float* mask_max  = (float*)(wsb + stats_off);                 // 24 f32
    float* batch_sum = (float*)(wsb + stats_off + 96);            // 4 f32
    int*   batch_fg  = (int*)  (wsb + stats_off + 96 + 16);       // 4 i32

    // zero the small stats region (ws is poisoned 0xAA before every call)
    hipMemsetAsync(mask_max, 0, 96 + 16 + 16, stream);

    k_rowpass<<<NM * HH, 256, 0, stream>>>(pred, lab, dbuf);
    k_colpass<<<NM * 16, 256, 0, stream>>>(dbuf, mask_max);
    k_final<<<(BB * HW) / 256, 256, 0, stream>>>(pred, lab, dbuf, mask_max,
                                                 batch_sum, batch_fg);
    k_finalize<<<1, 64, 0, stream>>>(batch_sum, batch_fg, (float*)d_out);
}

// Round 2
// 167.535 us; speedup vs baseline: 1.2074x; 1.2074x over previous
//
#include <hip/hip_runtime.h>
#include <hip/hip_bf16.h>

// Problem constants
#define HH 256
#define WW 256
#define BB 4
#define CC 3
#define HW 65536          // H*W
#define NM 24             // 2*B*C masks (0..11 lab, 12..23 pred)
#define BIGF 1e9f
#define LIMITF 331776.0f  // 576*576
#define EPSF 1e-5f

// ---------------------------------------------------------------------------
// Pass 1: row-wise squared distance to nearest zero, all 6 masks of one
// (batch,row) per block (lab classes 0..2, pred-argmax classes 0..2).
// Exact match to min_k f[i,k]+(j-k)^2 with f in {0,1e9}: nearest-zero
// distance^2, or exactly 1e9 if the row has no zeros.
// grid: 4*256 blocks (b,row), 256 threads (col).
// ---------------------------------------------------------------------------
__global__ __launch_bounds__(256) void k_rowpass(const float* __restrict__ pred,
                                                 const int* __restrict__ lab,
                                                 float* __restrict__ dbuf) {
    int blk = blockIdx.x;
    int b = blk >> 8;
    int i = blk & 255;
    int j = threadIdx.x;

    int lv = lab[(b << 16) + (i << 8) + j];
    const float* pb = pred + (((size_t)(b * 3)) << 16) + (i << 8) + j;
    float p0 = pb[0];
    float p1 = pb[(size_t)1 << 16];
    float p2 = pb[(size_t)2 << 16];
    int am = 0; float v = p0;
    if (p1 > v) { am = 1; v = p1; }
    if (p2 > v) { am = 2; }

    __shared__ unsigned long long zm[6][4];   // [mask][wave] zero-pixel bitmaps
    int w = threadIdx.x >> 6;
    #pragma unroll
    for (int c = 0; c < 3; ++c) {
        unsigned long long zl = __ballot(lv != c);
        unsigned long long zp = __ballot(am != c);
        if ((threadIdx.x & 63) == 0) { zm[c][w] = zl; zm[3 + c][w] = zp; }
    }
    __syncthreads();

    #pragma unroll
    for (int t = 0; t < 6; ++t) {
        int bestd = 512;  // sentinel > any possible distance (<=255)
        #pragma unroll
        for (int w2 = 0; w2 < 4; ++w2) {
            unsigned long long z = zm[t][w2];
            int base = w2 << 6;
            int rel = j - base;
            unsigned long long mle;   // bits at positions <= rel
            if (rel >= 63)      mle = ~0ULL;
            else if (rel < 0)   mle = 0ULL;
            else                mle = (2ULL << rel) - 1ULL;
            unsigned long long zl = z & mle;
            if (zl) {
                int p = base + 63 - __clzll(zl);
                int d = j - p;
                if (d < bestd) bestd = d;
            }
            unsigned long long zr = z & ~mle;
            if (zr) {
                int p = base + __ffsll(zr) - 1;
                int d = p - j;
                if (d < bestd) bestd = d;
            }
        }
        float d1 = (bestd >= 512) ? BIGF : (float)(bestd * bestd);
        int c = (t < 3) ? t : (t - 3);
        int m = ((t < 3) ? 0 : 12) + b * 3 + c;
        dbuf[(((size_t)m) << 16) + (i << 8) + j] = d1;
    }
}

// ---------------------------------------------------------------------------
// Pass 2: column-wise min-plus: d[i,j] = min_k d1[k,j]+(i-k)^2.
// One block owns 4 FULL columns of one mask (in-place safe: reads and writes
// touch only its own columns). 256x4 tile (4 KB LDS). Thread (jj=tid&3,
// ib=tid>>2) produces rows ib, ib+64, ib+128, ib+192 of column j0+jj; the
// k-loop amortizes one LDS broadcast read over 4 sub+fma+fmin updates.
// Per-mask max of d reduced via atomicMax for normalization.
// grid: 24*64 blocks, 256 threads → 6144 waves (24 waves/CU).
// ---------------------------------------------------------------------------
__global__ __launch_bounds__(256) void k_colpass(float* __restrict__ dbuf,
                                                 float* __restrict__ mask_max) {
    int blk = blockIdx.x;
    int m = blk >> 6;
    int j0 = (blk & 63) << 2;
    __shared__ float tile[256 * 4];   // [row][jj], 4 KB
    float* base = dbuf + (((size_t)m) << 16);

    #pragma unroll
    for (int it = 0; it < 4; ++it) {
        int idx = (it << 8) + threadIdx.x;
        int row = idx >> 2, jj = idx & 3;
        tile[idx] = base[(row << 8) + j0 + jj];
    }
    __syncthreads();

    int jj = threadIdx.x & 3;
    int ib = threadIdx.x >> 2;   // 0..63
    float i0 = (float)ib;
    float i1 = (float)(ib + 64);
    float i2 = (float)(ib + 128);
    float i3 = (float)(ib + 192);
    float m0 = 3e38f, m1 = 3e38f, m2 = 3e38f, m3 = 3e38f;

    #pragma unroll 8
    for (int k = 0; k < 256; ++k) {
        float fk = tile[(k << 2) + jj];   // 4 addresses/wave, broadcast, no conflict
        float fkf = (float)k;
        float t0 = i0 - fkf; m0 = fminf(m0, fmaf(t0, t0, fk));
        float t1 = i1 - fkf; m1 = fminf(m1, fmaf(t1, t1, fk));
        float t2 = i2 - fkf; m2 = fminf(m2, fmaf(t2, t2, fk));
        float t3 = i3 - fkf; m3 = fminf(m3, fmaf(t3, t3, fk));
    }

    int col = j0 + jj;
    base[((ib      ) << 8) + col] = m0;
    base[((ib +  64) << 8) + col] = m1;
    base[((ib + 128) << 8) + col] = m2;
    base[((ib + 192) << 8) + col] = m3;

    float lmax = fmaxf(fmaxf(m0, m1), fmaxf(m2, m3));
    #pragma unroll
    for (int off = 32; off; off >>= 1)
        lmax = fmaxf(lmax, __shfl_down(lmax, off, 64));
    __shared__ float wmax[4];
    if ((threadIdx.x & 63) == 0) wmax[threadIdx.x >> 6] = lmax;
    __syncthreads();
    if (threadIdx.x == 0) {
        float mx = fmaxf(fmaxf(wmax[0], wmax[1]), fmaxf(wmax[2], wmax[3]));
        atomicMax((int*)&mask_max[m], __float_as_int(mx));   // values >= 0
    }
}

// ---------------------------------------------------------------------------
// Per-pixel cosine sim + per-batch reduction.
// sim = (sp*sl + [argmax==lab]) / (sqrt(sp^2+1)*sqrt(sl^2+1)), where
// sp/sl = sum_c sqrt(d) * inv_norm, inv_norm = 1/(min(sqrt(dmax),LIMIT)+eps).
// grid: 1024 blocks x 256 (each block entirely inside one batch).
// ---------------------------------------------------------------------------
__global__ __launch_bounds__(256) void k_final(const float* __restrict__ pred,
                                               const int* __restrict__ lab,
                                               const float* __restrict__ dbuf,
                                               const float* __restrict__ mask_max,
                                               float* __restrict__ batch_sum,
                                               int* __restrict__ batch_fg) {
    __shared__ float inv[NM];
    if (threadIdx.x < NM) {
        float mx = sqrtf(mask_max[threadIdx.x]);
        inv[threadIdx.x] = 1.0f / (fminf(mx, LIMITF) + EPSF);
    }
    __syncthreads();

    int p = blockIdx.x * 256 + threadIdx.x;   // [0, B*HW)
    int b = p >> 16;
    int pix = p & 65535;

    int lv = lab[p];
    const float* pb = pred + (((size_t)(b * 3)) << 16) + pix;
    float p0 = pb[0];
    float p1 = pb[(size_t)1 << 16];
    float p2 = pb[(size_t)2 << 16];
    int am = 0; float v = p0;
    if (p1 > v) { am = 1; v = p1; }
    if (p2 > v) { am = 2; }

    float slab = 0.0f, spred = 0.0f;
    #pragma unroll
    for (int c = 0; c < 3; ++c) {
        int ml = b * 3 + c;
        float dl = dbuf[(((size_t)ml) << 16) + pix];
        slab += sqrtf(dl) * inv[ml];
        float dp = dbuf[(((size_t)(ml + 12)) << 16) + pix];
        spred += sqrtf(dp) * inv[ml + 12];
    }

    float dot = spred * slab + ((am == lv) ? 1.0f : 0.0f);
    float na = sqrtf(spred * spred + 1.0f);
    float nb = sqrtf(slab * slab + 1.0f);
    float sim = dot / (fmaxf(na, 1e-8f) * fmaxf(nb, 1e-8f));

    unsigned long long fg = __ballot(lv > 0);

    #pragma unroll
    for (int off = 32; off; off >>= 1)
        sim += __shfl_down(sim, off, 64);
    __shared__ float wsum[4];
    if ((threadIdx.x & 63) == 0) wsum[threadIdx.x >> 6] = sim;
    __syncthreads();
    if (threadIdx.x == 0)
        atomicAdd(&batch_sum[b], wsum[0] + wsum[1] + wsum[2] + wsum[3]);
    if ((threadIdx.x & 63) == 0 && fg)
        atomicOr(&batch_fg[b], 1);
}

// ---------------------------------------------------------------------------
// loss = sum_b has_fg ? (1 - mean sim) : 0, / B; nan_to_num.
// ---------------------------------------------------------------------------
__global__ void k_finalize(const float* __restrict__ batch_sum,
                           const int* __restrict__ batch_fg,
                           float* __restrict__ out) {
    if (threadIdx.x == 0 && blockIdx.x == 0) {
        float loss = 0.0f;
        for (int b = 0; b < BB; ++b) {
            float lb = 1.0f - batch_sum[b] * (1.0f / (float)HW);
            if (batch_fg[b]) loss += lb;
        }
        loss *= (1.0f / (float)BB);
        if (isnan(loss)) loss = 0.0f;
        else if (isinf(loss)) loss = (loss > 0.0f) ? 1.0f : 0.0f;
        out[0] = loss;
    }
}

extern "C" void kernel_launch(void* const* d_in, const int* in_sizes, int n_in,
                              void* d_out, int out_size, void* d_ws, size_t ws_size,
                              hipStream_t stream) {
    const float* pred = (const float*)d_in[0];   // [4,3,256,256] f32
    const int*   lab  = (const int*)d_in[1];     // [4,256,256] i32

    char* wsb = (char*)d_ws;
    float* dbuf      = (float*)wsb;                               // 24*65536 f32 = 6 MB
    size_t stats_off = (size_t)NM * HW * sizeof(float);
    float* mask_max  = (float*)(wsb + stats_off);                 // 24 f32
    float* batch_sum = (float*)(wsb + stats_off + 96);            // 4 f32
    int*   batch_fg  = (int*)  (wsb + stats_off + 96 + 16);       // 4 i32

    // zero the small stats region (ws is poisoned 0xAA before every call)
    hipMemsetAsync(mask_max, 0, 96 + 16 + 16, stream);

    k_rowpass<<<BB * HH, 256, 0, stream>>>(pred, lab, dbuf);
    k_colpass<<<NM * 64, 256, 0, stream>>>(dbuf, mask_max);
    k_final<<<(BB * HW) / 256, 256, 0, stream>>>(pred, lab, dbuf, mask_max,
                                                 batch_sum, batch_fg);
    k_finalize<<<1, 64, 0, stream>>>(batch_sum, batch_fg, (float*)d_out);
}

// Round 3
// 107.510 us; speedup vs baseline: 1.8815x; 1.5583x over previous
//
#include <hip/hip_runtime.h>
#include <hip/hip_bf16.h>

// Problem constants
#define HH 256
#define WW 256
#define BB 4
#define CC 3
#define HW 65536          // H*W
#define NM 24             // 2*B*C masks (0..11 lab, 12..23 pred)
#define BIGF 1e9f
#define LIMITF 331776.0f  // 576*576
#define EPSF 1e-5f

// ---------------------------------------------------------------------------
// Pass 1: row-wise squared distance to nearest zero, all 6 masks of one
// (batch,row) per block. Exact match to min_k f[i,k]+(j-k)^2 with
// f in {0,1e9}: nearest-zero distance^2, or exactly 1e9 if no zeros in row.
// grid: 4*256 blocks (b,row), 256 threads (col).
// ---------------------------------------------------------------------------
__global__ __launch_bounds__(256) void k_rowpass(const float* __restrict__ pred,
                                                 const int* __restrict__ lab,
                                                 float* __restrict__ dbuf) {
    int blk = blockIdx.x;
    int b = blk >> 8;
    int i = blk & 255;
    int j = threadIdx.x;

    int lv = lab[(b << 16) + (i << 8) + j];
    const float* pb = pred + (((size_t)(b * 3)) << 16) + (i << 8) + j;
    float p0 = pb[0];
    float p1 = pb[(size_t)1 << 16];
    float p2 = pb[(size_t)2 << 16];
    int am = 0; float v = p0;
    if (p1 > v) { am = 1; v = p1; }
    if (p2 > v) { am = 2; }

    __shared__ unsigned long long zm[6][4];   // [mask][wave] zero-pixel bitmaps
    int w = threadIdx.x >> 6;
    #pragma unroll
    for (int c = 0; c < 3; ++c) {
        unsigned long long zl = __ballot(lv != c);
        unsigned long long zp = __ballot(am != c);
        if ((threadIdx.x & 63) == 0) { zm[c][w] = zl; zm[3 + c][w] = zp; }
    }
    __syncthreads();

    #pragma unroll
    for (int t = 0; t < 6; ++t) {
        int bestd = 512;  // sentinel > any possible distance (<=255)
        #pragma unroll
        for (int w2 = 0; w2 < 4; ++w2) {
            unsigned long long z = zm[t][w2];
            int base = w2 << 6;
            int rel = j - base;
            unsigned long long mle;   // bits at positions <= rel
            if (rel >= 63)      mle = ~0ULL;
            else if (rel < 0)   mle = 0ULL;
            else                mle = (2ULL << rel) - 1ULL;
            unsigned long long zl = z & mle;
            if (zl) {
                int p = base + 63 - __clzll(zl);
                int d = j - p;
                if (d < bestd) bestd = d;
            }
            unsigned long long zr = z & ~mle;
            if (zr) {
                int p = base + __ffsll(zr) - 1;
                int d = p - j;
                if (d < bestd) bestd = d;
            }
        }
        float d1 = (bestd >= 512) ? BIGF : (float)(bestd * bestd);
        int c = (t < 3) ? t : (t - 3);
        int m = ((t < 3) ? 0 : 12) + b * 3 + c;
        dbuf[(((size_t)m) << 16) + (i << 8) + j] = d1;
    }
}

// ---------------------------------------------------------------------------
// Pass 2: column-wise min-plus: d[i,j] = min_k d1[k,j]+(i-k)^2.
// One block owns 4 FULL columns of one mask (in-place safe). 256x4 tile in
// LDS; each thread produces 4 outputs so the k-loop amortizes one LDS
// broadcast read over 4 sub+fma+fmin updates. Per-block max written to
// blkmax[blockIdx] — NO global atomics (same-line atomics serialized R2's
// k_colpass/k_final across XCDs).
// grid: 24*64 blocks, 256 threads.
// ---------------------------------------------------------------------------
__global__ __launch_bounds__(256) void k_colpass(float* __restrict__ dbuf,
                                                 float* __restrict__ blkmax) {
    int blk = blockIdx.x;
    int m = blk >> 6;
    int j0 = (blk & 63) << 2;
    __shared__ float tile[256 * 4];   // [row][jj], 4 KB
    float* base = dbuf + (((size_t)m) << 16);

    #pragma unroll
    for (int it = 0; it < 4; ++it) {
        int idx = (it << 8) + threadIdx.x;
        int row = idx >> 2, jj = idx & 3;
        tile[idx] = base[(row << 8) + j0 + jj];
    }
    __syncthreads();

    int jj = threadIdx.x & 3;
    int ib = threadIdx.x >> 2;   // 0..63
    float i0 = (float)ib;
    float i1 = (float)(ib + 64);
    float i2 = (float)(ib + 128);
    float i3 = (float)(ib + 192);
    float m0 = 3e38f, m1 = 3e38f, m2 = 3e38f, m3 = 3e38f;

    #pragma unroll 8
    for (int k = 0; k < 256; ++k) {
        float fk = tile[(k << 2) + jj];   // 4 addresses/wave, broadcast, no conflict
        float fkf = (float)k;
        float t0 = i0 - fkf; m0 = fminf(m0, fmaf(t0, t0, fk));
        float t1 = i1 - fkf; m1 = fminf(m1, fmaf(t1, t1, fk));
        float t2 = i2 - fkf; m2 = fminf(m2, fmaf(t2, t2, fk));
        float t3 = i3 - fkf; m3 = fminf(m3, fmaf(t3, t3, fk));
    }

    int col = j0 + jj;
    base[((ib      ) << 8) + col] = m0;
    base[((ib +  64) << 8) + col] = m1;
    base[((ib + 128) << 8) + col] = m2;
    base[((ib + 192) << 8) + col] = m3;

    float lmax = fmaxf(fmaxf(m0, m1), fmaxf(m2, m3));
    #pragma unroll
    for (int off = 32; off; off >>= 1)
        lmax = fmaxf(lmax, __shfl_down(lmax, off, 64));
    __shared__ float wmax[4];
    if ((threadIdx.x & 63) == 0) wmax[threadIdx.x >> 6] = lmax;
    __syncthreads();
    if (threadIdx.x == 0)
        blkmax[blk] = fmaxf(fmaxf(wmax[0], wmax[1]), fmaxf(wmax[2], wmax[3]));
}

// ---------------------------------------------------------------------------
// Reduce per-block maxes -> inv[m] = 1/(min(sqrt(max_d), LIMIT)+eps).
// grid: 24 blocks x 64 threads (one wave per mask).
// ---------------------------------------------------------------------------
__global__ __launch_bounds__(64) void k_maskmax(const float* __restrict__ blkmax,
                                                float* __restrict__ inv) {
    int m = blockIdx.x;
    float v = blkmax[(m << 6) + threadIdx.x];
    #pragma unroll
    for (int off = 32; off; off >>= 1)
        v = fmaxf(v, __shfl_down(v, off, 64));
    if (threadIdx.x == 0)
        inv[m] = 1.0f / (fminf(sqrtf(v), LIMITF) + EPSF);
}

// ---------------------------------------------------------------------------
// Per-pixel cosine sim, reduced to per-BLOCK partials (no global atomics).
// sim = (sp*sl + [argmax==lab]) / (sqrt(sp^2+1)*sqrt(sl^2+1)),
// sp/sl = sum_c sqrt(d) * inv[m]. b is block-uniform so inv loads scalarize.
// grid: 1024 blocks x 256 (blocks 256b..256b+255 cover batch b).
// ---------------------------------------------------------------------------
__global__ __launch_bounds__(256) void k_final(const float* __restrict__ pred,
                                               const int* __restrict__ lab,
                                               const float* __restrict__ dbuf,
                                               const float* __restrict__ inv,
                                               float* __restrict__ psum,
                                               int* __restrict__ pfg) {
    int b = blockIdx.x >> 8;                         // uniform per block
    int pix = ((blockIdx.x & 255) << 8) + threadIdx.x;

    int lv = lab[(b << 16) + pix];
    const float* pb = pred + (((size_t)(b * 3)) << 16) + pix;
    float p0 = pb[0];
    float p1 = pb[(size_t)1 << 16];
    float p2 = pb[(size_t)2 << 16];
    int am = 0; float v = p0;
    if (p1 > v) { am = 1; v = p1; }
    if (p2 > v) { am = 2; }

    float slab = 0.0f, spred = 0.0f;
    #pragma unroll
    for (int c = 0; c < 3; ++c) {
        int ml = b * 3 + c;
        float dl = dbuf[(((size_t)ml) << 16) + pix];
        slab += sqrtf(dl) * inv[ml];
        float dp = dbuf[(((size_t)(ml + 12)) << 16) + pix];
        spred += sqrtf(dp) * inv[ml + 12];
    }

    float dot = spred * slab + ((am == lv) ? 1.0f : 0.0f);
    float na = sqrtf(spred * spred + 1.0f);
    float nb = sqrtf(slab * slab + 1.0f);
    float sim = dot / (fmaxf(na, 1e-8f) * fmaxf(nb, 1e-8f));

    unsigned long long fg = __ballot(lv > 0);

    #pragma unroll
    for (int off = 32; off; off >>= 1)
        sim += __shfl_down(sim, off, 64);
    __shared__ float wsum[4];
    __shared__ int wfg[4];
    if ((threadIdx.x & 63) == 0) {
        wsum[threadIdx.x >> 6] = sim;
        wfg[threadIdx.x >> 6] = (fg != 0ULL) ? 1 : 0;
    }
    __syncthreads();
    if (threadIdx.x == 0) {
        psum[blockIdx.x] = wsum[0] + wsum[1] + wsum[2] + wsum[3];
        pfg[blockIdx.x] = wfg[0] | wfg[1] | wfg[2] | wfg[3];
    }
}

// ---------------------------------------------------------------------------
// Reduce 1024 block partials -> loss. Blocks 256b..256b+255 belong to batch
// b: wave w handles batch w (thread t: batch=t>>6, 4 strided partials each).
// ---------------------------------------------------------------------------
__global__ __launch_bounds__(256) void k_finalize(const float* __restrict__ psum,
                                                  const int* __restrict__ pfg,
                                                  float* __restrict__ out) {
    int t = threadIdx.x;
    int b = t >> 6, l = t & 63;
    int base = (b << 8) + l;
    float s = psum[base] + psum[base + 64] + psum[base + 128] + psum[base + 192];
    int f = pfg[base] | pfg[base + 64] | pfg[base + 128] | pfg[base + 192];
    #pragma unroll
    for (int off = 32; off; off >>= 1) {
        s += __shfl_down(s, off, 64);
        f |= __shfl_down(f, off, 64);
    }
    __shared__ float bsum[4];
    __shared__ int bfg[4];
    if (l == 0) { bsum[b] = s; bfg[b] = f; }
    __syncthreads();
    if (t == 0) {
        float loss = 0.0f;
        for (int bb = 0; bb < BB; ++bb) {
            float lb = 1.0f - bsum[bb] * (1.0f / (float)HW);
            if (bfg[bb]) loss += lb;
        }
        loss *= (1.0f / (float)BB);
        if (isnan(loss)) loss = 0.0f;
        else if (isinf(loss)) loss = (loss > 0.0f) ? 1.0f : 0.0f;
        out[0] = loss;
    }
}

extern "C" void kernel_launch(void* const* d_in, const int* in_sizes, int n_in,
                              void* d_out, int out_size, void* d_ws, size_t ws_size,
                              hipStream_t stream) {
    const float* pred = (const float*)d_in[0];   // [4,3,256,256] f32
    const int*   lab  = (const int*)d_in[1];     // [4,256,256] i32

    char* wsb = (char*)d_ws;
    float* dbuf   = (float*)wsb;                                  // 24*65536 f32 = 6 MB
    size_t off    = (size_t)NM * HW * sizeof(float);
    float* blkmax = (float*)(wsb + off);          off += 1536 * sizeof(float);
    float* inv    = (float*)(wsb + off);          off += 32 * sizeof(float);
    float* psum   = (float*)(wsb + off);          off += 1024 * sizeof(float);
    int*   pfg    = (int*)  (wsb + off);

    // Every scratch word is written before it is read — no memset needed.
    k_rowpass <<<BB * HH,  256, 0, stream>>>(pred, lab, dbuf);
    k_colpass <<<NM * 64,  256, 0, stream>>>(dbuf, blkmax);
    k_maskmax <<<NM,        64, 0, stream>>>(blkmax, inv);
    k_final   <<<BB * 256, 256, 0, stream>>>(pred, lab, dbuf, inv, psum, pfg);
    k_finalize<<<1,        256, 0, stream>>>(psum, pfg, (float*)d_out);
}

// Round 4
// 89.766 us; speedup vs baseline: 2.2534x; 1.1977x over previous
//
#include <hip/hip_runtime.h>
#include <hip/hip_bf16.h>

// Problem constants
#define HH 256
#define WW 256
#define BB 4
#define CC 3
#define HW 65536          // H*W
#define NM 24             // 2*B*C masks (0..11 lab, 12..23 pred)
#define BIGF 1e9f
#define LIMITF 331776.0f  // 576*576
#define EPSF 1e-5f

// ---------------------------------------------------------------------------
// Pass 1: row-wise squared distance to nearest zero, all 6 masks of one
// (batch,row) per block. Stores g[i,j] = d1[i,j] + i^2  (the +i^2 is the
// algebraic fold for pass 2: d1[k]+(i-k)^2 = (d1[k]+k^2) - 2ik + i^2).
// Exact int arithmetic (<= 2*255^2 + 255^2 < 2^24) for non-BIG values.
// grid: 4*256 blocks (b,row), 256 threads (col).
// ---------------------------------------------------------------------------
__global__ __launch_bounds__(256) void k_rowpass(const float* __restrict__ pred,
                                                 const int* __restrict__ lab,
                                                 float* __restrict__ dbuf) {
    int blk = blockIdx.x;
    int b = blk >> 8;
    int i = blk & 255;
    int j = threadIdx.x;
    int ii = i * i;

    int lv = lab[(b << 16) + (i << 8) + j];
    const float* pb = pred + (((size_t)(b * 3)) << 16) + (i << 8) + j;
    float p0 = pb[0];
    float p1 = pb[(size_t)1 << 16];
    float p2 = pb[(size_t)2 << 16];
    int am = 0; float v = p0;
    if (p1 > v) { am = 1; v = p1; }
    if (p2 > v) { am = 2; }

    __shared__ unsigned long long zm[6][4];   // [mask][wave] zero-pixel bitmaps
    int w = threadIdx.x >> 6;
    #pragma unroll
    for (int c = 0; c < 3; ++c) {
        unsigned long long zl = __ballot(lv != c);
        unsigned long long zp = __ballot(am != c);
        if ((threadIdx.x & 63) == 0) { zm[c][w] = zl; zm[3 + c][w] = zp; }
    }
    __syncthreads();

    #pragma unroll
    for (int t = 0; t < 6; ++t) {
        int bestd = 512;  // sentinel > any possible distance (<=255)
        #pragma unroll
        for (int w2 = 0; w2 < 4; ++w2) {
            unsigned long long z = zm[t][w2];
            int base = w2 << 6;
            int rel = j - base;
            unsigned long long mle;   // bits at positions <= rel
            if (rel >= 63)      mle = ~0ULL;
            else if (rel < 0)   mle = 0ULL;
            else                mle = (2ULL << rel) - 1ULL;
            unsigned long long zl = z & mle;
            if (zl) {
                int p = base + 63 - __clzll(zl);
                int d = j - p;
                if (d < bestd) bestd = d;
            }
            unsigned long long zr = z & ~mle;
            if (zr) {
                int p = base + __ffsll(zr) - 1;
                int d = p - j;
                if (d < bestd) bestd = d;
            }
        }
        // g = d1 + i^2 (exact int path), or BIG + i^2 (one fp32 rounding)
        float g = (bestd >= 512) ? (BIGF + (float)ii)
                                 : (float)(bestd * bestd + ii);
        int c = (t < 3) ? t : (t - 3);
        int m = ((t < 3) ? 0 : 12) + b * 3 + c;
        dbuf[(((size_t)m) << 16) + (i << 8) + j] = g;
    }
}

// ---------------------------------------------------------------------------
// Pass 2: column-wise min-plus via the folded form:
//   d[i,j] = min_k (g[k,j] - 2ik) + i^2,  g from pass 1.
// One block owns 8 FULL columns of one mask (in-place safe). 256x8 g-tile in
// LDS; each thread holds 8 accumulators (rows ib+32r of column j0+jj) so the
// inner loop is exactly fma+min per (i,k) pair, with one ds_read + one kf
// add amortized over 8 outputs. Per-block max -> blkmax (no global atomics).
// grid: 24*32 blocks, 256 threads.
// ---------------------------------------------------------------------------
__global__ __launch_bounds__(256) void k_colpass(float* __restrict__ dbuf,
                                                 float* __restrict__ blkmax) {
    int blk = blockIdx.x;
    int m = blk >> 5;
    int j0 = (blk & 31) << 3;
    __shared__ float tile[256 * 8];   // g[row][jj], 8 KB
    float* base = dbuf + (((size_t)m) << 16);

    #pragma unroll
    for (int it = 0; it < 8; ++it) {
        int idx = (it << 8) + threadIdx.x;
        int row = idx >> 3, jj = idx & 7;
        tile[idx] = base[(row << 8) + j0 + jj];
    }
    __syncthreads();

    int jj = threadIdx.x & 7;
    int ib = threadIdx.x >> 3;   // 0..31
    float acc[8], m2i[8];
    #pragma unroll
    for (int r = 0; r < 8; ++r) {
        acc[r] = 3e38f;
        m2i[r] = -2.0f * (float)(ib + (r << 5));
    }

    float kf = 0.0f;
    #pragma unroll 8
    for (int k = 0; k < 256; ++k) {
        float gk = tile[(k << 3) + jj];   // 8 addrs, 8 banks, broadcast: no conflict
        #pragma unroll
        for (int r = 0; r < 8; ++r)
            acc[r] = fminf(acc[r], fmaf(m2i[r], kf, gk));
        kf += 1.0f;
    }

    int col = j0 + jj;
    float lmax = 0.0f;
    #pragma unroll
    for (int r = 0; r < 8; ++r) {
        int i = ib + (r << 5);
        float d = acc[r] + (float)(i * i);
        base[(i << 8) + col] = d;
        lmax = fmaxf(lmax, d);
    }

    #pragma unroll
    for (int off = 32; off; off >>= 1)
        lmax = fmaxf(lmax, __shfl_down(lmax, off, 64));
    __shared__ float wmax[4];
    if ((threadIdx.x & 63) == 0) wmax[threadIdx.x >> 6] = lmax;
    __syncthreads();
    if (threadIdx.x == 0)
        blkmax[blk] = fmaxf(fmaxf(wmax[0], wmax[1]), fmaxf(wmax[2], wmax[3]));
}

// ---------------------------------------------------------------------------
// Per-pixel cosine sim, reduced to per-BLOCK partials (no global atomics).
// Prologue reduces blkmax (24 masks x 32 blocks) -> inv[m] in LDS, replacing
// the separate k_maskmax launch.
// sim = (sp*sl + [argmax==lab]) / (sqrt(sp^2+1)*sqrt(sl^2+1)),
// sp/sl = sum_c sqrt(d) * inv[m].
// grid: 1024 blocks x 256 (blocks 256b..256b+255 cover batch b).
// ---------------------------------------------------------------------------
__global__ __launch_bounds__(256) void k_final(const float* __restrict__ pred,
                                               const int* __restrict__ lab,
                                               const float* __restrict__ dbuf,
                                               const float* __restrict__ blkmax,
                                               float* __restrict__ psum,
                                               int* __restrict__ pfg) {
    __shared__ float inv[NM];
    if (threadIdx.x < NM) {
        const float* bm = blkmax + (threadIdx.x << 5);
        float v = 0.0f;
        #pragma unroll
        for (int s = 0; s < 32; ++s) v = fmaxf(v, bm[s]);
        inv[threadIdx.x] = 1.0f / (fminf(sqrtf(v), LIMITF) + EPSF);
    }
    __syncthreads();

    int b = blockIdx.x >> 8;                         // uniform per block
    int pix = ((blockIdx.x & 255) << 8) + threadIdx.x;

    int lv = lab[(b << 16) + pix];
    const float* pb = pred + (((size_t)(b * 3)) << 16) + pix;
    float p0 = pb[0];
    float p1 = pb[(size_t)1 << 16];
    float p2 = pb[(size_t)2 << 16];
    int am = 0; float v = p0;
    if (p1 > v) { am = 1; v = p1; }
    if (p2 > v) { am = 2; }

    float slab = 0.0f, spred = 0.0f;
    #pragma unroll
    for (int c = 0; c < 3; ++c) {
        int ml = b * 3 + c;
        float dl = dbuf[(((size_t)ml) << 16) + pix];
        slab += sqrtf(dl) * inv[ml];
        float dp = dbuf[(((size_t)(ml + 12)) << 16) + pix];
        spred += sqrtf(dp) * inv[ml + 12];
    }

    float dot = spred * slab + ((am == lv) ? 1.0f : 0.0f);
    float na = sqrtf(spred * spred + 1.0f);
    float nb = sqrtf(slab * slab + 1.0f);
    float sim = dot / (fmaxf(na, 1e-8f) * fmaxf(nb, 1e-8f));

    unsigned long long fg = __ballot(lv > 0);

    #pragma unroll
    for (int off = 32; off; off >>= 1)
        sim += __shfl_down(sim, off, 64);
    __shared__ float wsum[4];
    __shared__ int wfg[4];
    if ((threadIdx.x & 63) == 0) {
        wsum[threadIdx.x >> 6] = sim;
        wfg[threadIdx.x >> 6] = (fg != 0ULL) ? 1 : 0;
    }
    __syncthreads();
    if (threadIdx.x == 0) {
        psum[blockIdx.x] = wsum[0] + wsum[1] + wsum[2] + wsum[3];
        pfg[blockIdx.x] = wfg[0] | wfg[1] | wfg[2] | wfg[3];
    }
}

// ---------------------------------------------------------------------------
// Reduce 1024 block partials -> loss. Blocks 256b..256b+255 belong to batch
// b: thread t handles batch t>>6, 4 strided partials each.
// ---------------------------------------------------------------------------
__global__ __launch_bounds__(256) void k_finalize(const float* __restrict__ psum,
                                                  const int* __restrict__ pfg,
                                                  float* __restrict__ out) {
    int t = threadIdx.x;
    int b = t >> 6, l = t & 63;
    int base = (b << 8) + l;
    float s = psum[base] + psum[base + 64] + psum[base + 128] + psum[base + 192];
    int f = pfg[base] | pfg[base + 64] | pfg[base + 128] | pfg[base + 192];
    #pragma unroll
    for (int off = 32; off; off >>= 1) {
        s += __shfl_down(s, off, 64);
        f |= __shfl_down(f, off, 64);
    }
    __shared__ float bsum[4];
    __shared__ int bfg[4];
    if (l == 0) { bsum[b] = s; bfg[b] = f; }
    __syncthreads();
    if (t == 0) {
        float loss = 0.0f;
        for (int bb = 0; bb < BB; ++bb) {
            float lb = 1.0f - bsum[bb] * (1.0f / (float)HW);
            if (bfg[bb]) loss += lb;
        }
        loss *= (1.0f / (float)BB);
        if (isnan(loss)) loss = 0.0f;
        else if (isinf(loss)) loss = (loss > 0.0f) ? 1.0f : 0.0f;
        out[0] = loss;
    }
}

extern "C" void kernel_launch(void* const* d_in, const int* in_sizes, int n_in,
                              void* d_out, int out_size, void* d_ws, size_t ws_size,
                              hipStream_t stream) {
    const float* pred = (const float*)d_in[0];   // [4,3,256,256] f32
    const int*   lab  = (const int*)d_in[1];     // [4,256,256] i32

    char* wsb = (char*)d_ws;
    float* dbuf   = (float*)wsb;                                  // 24*65536 f32 = 6 MB
    size_t off    = (size_t)NM * HW * sizeof(float);
    float* blkmax = (float*)(wsb + off);          off += 768 * sizeof(float);
    float* psum   = (float*)(wsb + off);          off += 1024 * sizeof(float);
    int*   pfg    = (int*)  (wsb + off);

    // Every scratch word is written before it is read — no memset needed.
    k_rowpass <<<BB * HH,  256, 0, stream>>>(pred, lab, dbuf);
    k_colpass <<<NM * 32,  256, 0, stream>>>(dbuf, blkmax);
    k_final   <<<BB * 256, 256, 0, stream>>>(pred, lab, dbuf, blkmax, psum, pfg);
    k_finalize<<<1,        256, 0, stream>>>(psum, pfg, (float*)d_out);
}

// Round 5
// 84.343 us; speedup vs baseline: 2.3983x; 1.0643x over previous
//
#include <hip/hip_runtime.h>
#include <hip/hip_bf16.h>

// Problem constants
#define HH 256
#define WW 256
#define BB 4
#define CC 3
#define HW 65536          // H*W
#define NM 24             // 2*B*C masks (0..11 lab, 12..23 pred)
#define BIGF 1e9f
#define LIMITF 331776.0f  // 576*576
#define EPSF 1e-5f

// ---------------------------------------------------------------------------
// Pass 1: row-wise squared distance to nearest zero, all 6 masks of one
// (batch,row) per block. Stores RAW d1 (bit-exact vs reference row pass:
// exact small ints, or exactly 1e9 when the row has no zeros).
// grid: 4*256 blocks (b,row), 256 threads (col).
// ---------------------------------------------------------------------------
__global__ __launch_bounds__(256) void k_rowpass(const float* __restrict__ pred,
                                                 const int* __restrict__ lab,
                                                 float* __restrict__ dbuf) {
    int blk = blockIdx.x;
    int b = blk >> 8;
    int i = blk & 255;
    int j = threadIdx.x;

    int lv = lab[(b << 16) + (i << 8) + j];
    const float* pb = pred + (((size_t)(b * 3)) << 16) + (i << 8) + j;
    float p0 = pb[0];
    float p1 = pb[(size_t)1 << 16];
    float p2 = pb[(size_t)2 << 16];
    int am = 0; float v = p0;
    if (p1 > v) { am = 1; v = p1; }
    if (p2 > v) { am = 2; }

    __shared__ unsigned long long zm[6][4];   // [mask][wave] zero-pixel bitmaps
    int w = threadIdx.x >> 6;
    #pragma unroll
    for (int c = 0; c < 3; ++c) {
        unsigned long long zl = __ballot(lv != c);
        unsigned long long zp = __ballot(am != c);
        if ((threadIdx.x & 63) == 0) { zm[c][w] = zl; zm[3 + c][w] = zp; }
    }
    __syncthreads();

    #pragma unroll
    for (int t = 0; t < 6; ++t) {
        int bestd = 512;  // sentinel > any possible distance (<=255)
        #pragma unroll
        for (int w2 = 0; w2 < 4; ++w2) {
            unsigned long long z = zm[t][w2];
            int base = w2 << 6;
            int rel = j - base;
            unsigned long long mle;   // bits at positions <= rel
            if (rel >= 63)      mle = ~0ULL;
            else if (rel < 0)   mle = 0ULL;
            else                mle = (2ULL << rel) - 1ULL;
            unsigned long long zl = z & mle;
            if (zl) {
                int p = base + 63 - __clzll(zl);
                int d = j - p;
                if (d < bestd) bestd = d;
            }
            unsigned long long zr = z & ~mle;
            if (zr) {
                int p = base + __ffsll(zr) - 1;
                int d = p - j;
                if (d < bestd) bestd = d;
            }
        }
        float d1 = (bestd >= 512) ? BIGF : (float)(bestd * bestd);
        int c = (t < 3) ? t : (t - 3);
        int m = ((t < 3) ? 0 : 12) + b * 3 + c;
        dbuf[(((size_t)m) << 16) + (i << 8) + j] = d1;
    }
}

// ---------------------------------------------------------------------------
// Pass 2: column-wise min-plus with EXACT windowing:
//   d[i,j] = min_k d1[k,j]+(i-k)^2.
// Since d1[k] >= 0 and k=i is a candidate, any |i-k| > sqrt(d1[i]) cannot
// beat d1[i] >= true min, so scanning k in [i-R, i+R], R = floor(sqrt(d1[i]))+1
// (clamped to full range; BIG rows degrade to the exact 256-scan) is exact.
// fma(dk,dk,d1[k]): product exact (int <= 2^16), one rounding — bit-identical
// to reference. One block owns 8 FULL columns (in-place safe). Tile padded
// to stride 9 so windowed per-lane LDS reads spread across banks.
// grid: 24*32 blocks, 256 threads.
// ---------------------------------------------------------------------------
__global__ __launch_bounds__(256) void k_colpass(float* __restrict__ dbuf,
                                                 float* __restrict__ blkmax) {
    int blk = blockIdx.x;
    int m = blk >> 5;
    int j0 = (blk & 31) << 3;
    __shared__ float tile[256 * 9];   // [row][jj], stride 9 (pad), 9 KB
    float* base = dbuf + (((size_t)m) << 16);

    // Stage 256x8 column slab via float4 (2 per thread), scatter to padded LDS.
    #pragma unroll
    for (int it = 0; it < 2; ++it) {
        int f = (it << 8) + threadIdx.x;   // float4 index 0..511
        int row = f >> 1, half = f & 1;
        float4 v = *(const float4*)(base + (row << 8) + j0 + (half << 2));
        int lb = row * 9 + (half << 2);
        tile[lb + 0] = v.x; tile[lb + 1] = v.y;
        tile[lb + 2] = v.z; tile[lb + 3] = v.w;
    }
    __syncthreads();

    int jj = threadIdx.x & 7;
    int ib = threadIdx.x >> 3;   // 0..31
    float lmax = 0.0f;

    #pragma unroll
    for (int r = 0; r < 8; ++r) {
        int i = ib + (r << 5);
        float di = tile[i * 9 + jj];
        float acc = di;                    // k = i candidate
        int R = (int)sqrtf(di) + 1;        // over-estimate is still exact
        if (R > 255) R = 255;              // BIG -> full scan
        int k0 = i - R; if (k0 < 0) k0 = 0;
        int k1 = i + R; if (k1 > 255) k1 = 255;
        for (int k = k0; k <= k1; ++k) {
            float dk = (float)(k - i);
            acc = fminf(acc, fmaf(dk, dk, tile[k * 9 + jj]));
        }
        base[(i << 8) + j0 + jj] = acc;
        lmax = fmaxf(lmax, acc);
    }

    #pragma unroll
    for (int off = 32; off; off >>= 1)
        lmax = fmaxf(lmax, __shfl_down(lmax, off, 64));
    __shared__ float wmax[4];
    if ((threadIdx.x & 63) == 0) wmax[threadIdx.x >> 6] = lmax;
    __syncthreads();
    if (threadIdx.x == 0)
        blkmax[blk] = fmaxf(fmaxf(wmax[0], wmax[1]), fmaxf(wmax[2], wmax[3]));
}

// ---------------------------------------------------------------------------
// Per-pixel cosine sim, reduced to per-BLOCK partials (no global atomics).
// Prologue reduces blkmax (24 masks x 32 blocks) -> inv[m] in LDS.
// sim = (sp*sl + [argmax==lab]) / (sqrt(sp^2+1)*sqrt(sl^2+1)),
// sp/sl = sum_c sqrt(d) * inv[m].
// grid: 1024 blocks x 256 (blocks 256b..256b+255 cover batch b).
// ---------------------------------------------------------------------------
__global__ __launch_bounds__(256) void k_final(const float* __restrict__ pred,
                                               const int* __restrict__ lab,
                                               const float* __restrict__ dbuf,
                                               const float* __restrict__ blkmax,
                                               float* __restrict__ psum,
                                               int* __restrict__ pfg) {
    __shared__ float inv[NM];
    if (threadIdx.x < NM) {
        const float* bm = blkmax + (threadIdx.x << 5);
        float v = 0.0f;
        #pragma unroll
        for (int s = 0; s < 32; ++s) v = fmaxf(v, bm[s]);
        inv[threadIdx.x] = 1.0f / (fminf(sqrtf(v), LIMITF) + EPSF);
    }
    __syncthreads();

    int b = blockIdx.x >> 8;                         // uniform per block
    int pix = ((blockIdx.x & 255) << 8) + threadIdx.x;

    int lv = lab[(b << 16) + pix];
    const float* pb = pred + (((size_t)(b * 3)) << 16) + pix;
    float p0 = pb[0];
    float p1 = pb[(size_t)1 << 16];
    float p2 = pb[(size_t)2 << 16];
    int am = 0; float v = p0;
    if (p1 > v) { am = 1; v = p1; }
    if (p2 > v) { am = 2; }

    float slab = 0.0f, spred = 0.0f;
    #pragma unroll
    for (int c = 0; c < 3; ++c) {
        int ml = b * 3 + c;
        float dl = dbuf[(((size_t)ml) << 16) + pix];
        slab += sqrtf(dl) * inv[ml];
        float dp = dbuf[(((size_t)(ml + 12)) << 16) + pix];
        spred += sqrtf(dp) * inv[ml + 12];
    }

    float dot = spred * slab + ((am == lv) ? 1.0f : 0.0f);
    float na = sqrtf(spred * spred + 1.0f);
    float nb = sqrtf(slab * slab + 1.0f);
    float sim = dot / (fmaxf(na, 1e-8f) * fmaxf(nb, 1e-8f));

    unsigned long long fg = __ballot(lv > 0);

    #pragma unroll
    for (int off = 32; off; off >>= 1)
        sim += __shfl_down(sim, off, 64);
    __shared__ float wsum[4];
    __shared__ int wfg[4];
    if ((threadIdx.x & 63) == 0) {
        wsum[threadIdx.x >> 6] = sim;
        wfg[threadIdx.x >> 6] = (fg != 0ULL) ? 1 : 0;
    }
    __syncthreads();
    if (threadIdx.x == 0) {
        psum[blockIdx.x] = wsum[0] + wsum[1] + wsum[2] + wsum[3];
        pfg[blockIdx.x] = wfg[0] | wfg[1] | wfg[2] | wfg[3];
    }
}

// ---------------------------------------------------------------------------
// Reduce 1024 block partials -> loss.
// ---------------------------------------------------------------------------
__global__ __launch_bounds__(256) void k_finalize(const float* __restrict__ psum,
                                                  const int* __restrict__ pfg,
                                                  float* __restrict__ out) {
    int t = threadIdx.x;
    int b = t >> 6, l = t & 63;
    int base = (b << 8) + l;
    float s = psum[base] + psum[base + 64] + psum[base + 128] + psum[base + 192];
    int f = pfg[base] | pfg[base + 64] | pfg[base + 128] | pfg[base + 192];
    #pragma unroll
    for (int off = 32; off; off >>= 1) {
        s += __shfl_down(s, off, 64);
        f |= __shfl_down(f, off, 64);
    }
    __shared__ float bsum[4];
    __shared__ int bfg[4];
    if (l == 0) { bsum[b] = s; bfg[b] = f; }
    __syncthreads();
    if (t == 0) {
        float loss = 0.0f;
        for (int bb = 0; bb < BB; ++bb) {
            float lb = 1.0f - bsum[bb] * (1.0f / (float)HW);
            if (bfg[bb]) loss += lb;
        }
        loss *= (1.0f / (float)BB);
        if (isnan(loss)) loss = 0.0f;
        else if (isinf(loss)) loss = (loss > 0.0f) ? 1.0f : 0.0f;
        out[0] = loss;
    }
}

extern "C" void kernel_launch(void* const* d_in, const int* in_sizes, int n_in,
                              void* d_out, int out_size, void* d_ws, size_t ws_size,
                              hipStream_t stream) {
    const float* pred = (const float*)d_in[0];   // [4,3,256,256] f32
    const int*   lab  = (const int*)d_in[1];     // [4,256,256] i32

    char* wsb = (char*)d_ws;
    float* dbuf   = (float*)wsb;                                  // 24*65536 f32 = 6 MB
    size_t off    = (size_t)NM * HW * sizeof(float);
    float* blkmax = (float*)(wsb + off);          off += 768 * sizeof(float);
    float* psum   = (float*)(wsb + off);          off += 1024 * sizeof(float);
    int*   pfg    = (int*)  (wsb + off);

    // Every scratch word is written before it is read — no memset needed.
    k_rowpass <<<BB * HH,  256, 0, stream>>>(pred, lab, dbuf);
    k_colpass <<<NM * 32,  256, 0, stream>>>(dbuf, blkmax);
    k_final   <<<BB * 256, 256, 0, stream>>>(pred, lab, dbuf, blkmax, psum, pfg);
    k_finalize<<<1,        256, 0, stream>>>(psum, pfg, (float*)d_out);
}